// Round 11
// baseline (373.613 us; speedup 1.0000x reference)
//
#include <hip/hip_runtime.h>
#include <math.h>

#define NN 4096
#define RB 128  // readout stage-1 blocks

typedef __attribute__((ext_vector_type(8))) short bf16x8;
typedef __attribute__((ext_vector_type(4))) float f32x4;

// ---------- helpers ----------
__device__ __forceinline__ unsigned encf(float f) {
  unsigned u = __float_as_uint(f);
  return (u & 0x80000000u) ? ~u : (u | 0x80000000u);
}
__device__ __forceinline__ float decf(unsigned u) {
  return __uint_as_float((u & 0x80000000u) ? (u ^ 0x80000000u) : ~u);
}
__device__ __forceinline__ unsigned short f2bf(float f) {
  unsigned u = __float_as_uint(f);
  return (unsigned short)((u + 0x7fffu + ((u >> 16) & 1u)) >> 16);
}

// ---------- init ----------
__global__ void k_init(float* out, unsigned* dmax) {
  int t = blockIdx.x * 256 + threadIdx.x;
  if (t < 512) out[t] = 0.f;
  if (t == 0) *dmax = 0u;
}

// ---------- pos = img @ Wp + bp ----------
__global__ void k_pos(const float* img, const float* Wp, const float* bp, float* pos) {
  int t = blockIdx.x * 256 + threadIdx.x;
  if (t >= NN * 12) return;
  int i = t / 12, d = t % 12;
  float s = bp[d];
#pragma unroll
  for (int k = 0; k < 6; ++k) s += img[i * 6 + k] * Wp[k * 12 + d];
  pos[t] = s;
}

// ---------- attention, d=12, LDS-tiled keys, branch-free softmax ----------
__global__ __launch_bounds__(256) void k_attn3(const float* pos, float* out) {
  __shared__ float sp[12][256];
  int t = threadIdx.x, lane = t & 63, w = t >> 6;
  int ib = blockIdx.x * 8 + w * 2;  // 2 rows per wave, 8 per block
  float pi[2][12];
#pragma unroll
  for (int r = 0; r < 2; ++r)
#pragma unroll
    for (int d = 0; d < 12; ++d) pi[r][d] = pos[(ib + r) * 12 + d] * 0.28867513459481287f;
  float sl[2] = {0.f, 0.f};
  float acc[2][12] = {};
  const float4* p4 = (const float4*)pos;
  for (int kt = 0; kt < NN; kt += 256) {
    __syncthreads();  // previous tile fully consumed
    int j = kt + t;
    float4 a = p4[j * 3 + 0], b = p4[j * 3 + 1], c = p4[j * 3 + 2];
    sp[0][t] = a.x; sp[1][t] = a.y; sp[2][t] = a.z; sp[3][t] = a.w;
    sp[4][t] = b.x; sp[5][t] = b.y; sp[6][t] = b.z; sp[7][t] = b.w;
    sp[8][t] = c.x; sp[9][t] = c.y; sp[10][t] = c.z; sp[11][t] = c.w;
    __syncthreads();
#pragma unroll
    for (int q = 0; q < 4; ++q) {
      int jj = q * 64 + lane;
      float pj[12];
#pragma unroll
      for (int d = 0; d < 12; ++d) pj[d] = sp[d][jj];
#pragma unroll
      for (int r = 0; r < 2; ++r) {
        float s = 0.f;
#pragma unroll
        for (int d = 0; d < 12; ++d) s = fmaf(pi[r][d], pj[d], s);
        float e = __expf(s);
        sl[r] += e;
#pragma unroll
        for (int d = 0; d < 12; ++d) acc[r][d] = fmaf(e, pj[d], acc[r][d]);
      }
    }
  }
#pragma unroll
  for (int r = 0; r < 2; ++r) {
    float s = sl[r];
#pragma unroll
    for (int o = 32; o > 0; o >>= 1) s += __shfl_xor(s, o);
    float ad[12];
#pragma unroll
    for (int d = 0; d < 12; ++d) {
      ad[d] = acc[r][d];
#pragma unroll
      for (int o = 32; o > 0; o >>= 1) ad[d] += __shfl_xor(ad[d], o);
    }
    if (lane == 0) {
      float inv = 1.f / s;
#pragma unroll
      for (int d = 0; d < 12; ++d) out[(ib + r) * 12 + d] = ad[d] * inv;
    }
  }
}

// ---------- fused layernorms + sumsq + bf16 convert ----------
__global__ __launch_bounds__(256) void k_lnx(const float* f, const float* g, const float* b,
                                             const float* p, const float* pg, const float* pb,
                                             float* x0, unsigned short* x0h, float* sqv) {
  __shared__ float row[512];
  __shared__ float red[256];
  int i = blockIdx.x, t = threadIdx.x;
  float v1 = f[i * 500 + t];
  float v2 = (t < 244) ? f[i * 500 + 256 + t] : 0.f;
  red[t] = v1 + v2; __syncthreads();
  for (int s = 128; s > 0; s >>= 1) { if (t < s) red[t] += red[t + s]; __syncthreads(); }
  float m = red[0] * (1.f / 500.f); __syncthreads();
  float d1 = v1 - m, d2 = v2 - m;
  red[t] = d1 * d1 + ((t < 244) ? d2 * d2 : 0.f); __syncthreads();
  for (int s = 128; s > 0; s >>= 1) { if (t < s) red[t] += red[t + s]; __syncthreads(); }
  float scale = 1.f / sqrtf(red[0] * (1.f / 500.f) + 1e-5f);
  row[t] = d1 * scale * g[t] + b[t];
  if (t < 244) row[256 + t] = d2 * scale * g[256 + t] + b[256 + t];
  if (t >= 244) {  // threads 244..255 handle the 12-wide pos layernorm
    int tt = t - 244;
    float pv[12], pm = 0.f;
#pragma unroll
    for (int d = 0; d < 12; ++d) { pv[d] = p[i * 12 + d]; pm += pv[d]; }
    pm *= (1.f / 12.f);
    float pvar = 0.f;
#pragma unroll
    for (int d = 0; d < 12; ++d) { float dd = pv[d] - pm; pvar += dd * dd; }
    pvar *= (1.f / 12.f);
    float ps = 1.f / sqrtf(pvar + 1e-5f);
    row[500 + tt] = (pv[tt] - pm) * ps * pg[tt] + pb[tt];
  }
  __syncthreads();
  float a = row[t], c = row[256 + t];
  red[t] = a * a + c * c; __syncthreads();
  for (int s = 128; s > 0; s >>= 1) { if (t < s) red[t] += red[t + s]; __syncthreads(); }
  if (t == 0) sqv[i] = red[0];
  x0[(size_t)i * 512 + t] = a;
  x0[(size_t)i * 512 + 256 + t] = c;
  x0h[(size_t)i * 512 + t] = f2bf(a);
  x0h[(size_t)i * 512 + 256 + t] = f2bf(c);
}

// ---------- MFMA d2 tiles (64x64, upper tile pairs): max / mask pass ----------
// 64^2 tiles -> 2080 blocks (8.1/CU): latency hidden by TLP (m114), not ILP.
// 4 waves, each 32x32 output (2x2 16x16 frags, 16 AGPR). Single-buffer 16KB LDS,
// global_load_lds w=16, source pre-swizzled chunk (lane&7)^(row&7), reads same XOR.
// Pass A also records per-tile min over gi<gj (exact fp32); pass B skips GEMM when
// tileMin >= thr (whole tile zero) and zeroes the mirror tile -> no memset needed.
#define BK 64
#define TN 64
template <bool MASK>
__global__ __launch_bounds__(256, 6) void k_d2m(const unsigned short* X, const float* sqv,
                                                unsigned* dmax, float* tileMin,
                                                unsigned char* ATm) {
  __shared__ unsigned short As[TN * BK];
  __shared__ unsigned short Bs[TN * BK];
  __shared__ float wmin[4];
  const int NT = NN / TN;  // 64
  int bid0 = blockIdx.x;
  int bid = (bid0 & 7) * 260 + (bid0 >> 3);  // 2080 = 8*260, bijective
  int ti = 0, rem = bid;
  while (rem >= NT - ti) { rem -= NT - ti; ++ti; }
  int tj = ti + rem;
  int t = threadIdx.x, lane = t & 63, w = t >> 6;
  int wr = w >> 1, wc = w & 1;  // wave's 32x32 sub-tile
  const unsigned short* Abase = X + (size_t)ti * TN * 512;
  const unsigned short* Bbase = X + (size_t)tj * TN * 512;
  int lr = lane >> 3, lc = lane & 7;

  float thr = 0.f;
  if (MASK) {
    thr = 0.5f * decf(*dmax);
    uint4 z = make_uint4(0u, 0u, 0u, 0u);
    if (ti != tj) {  // mirror tile (rows ti, cols tj) never receives mask writes
      int r = t >> 2, c4 = t & 3;
      *(uint4*)(ATm + (size_t)(ti * TN + r) * NN + tj * TN + c4 * 16) = z;
    }
    if (tileMin[blockIdx.x] >= thr) {  // no element can pass -> zero tile, skip GEMM
      int r = t >> 2, c4 = t & 3;
      *(uint4*)(ATm + (size_t)(tj * TN + r) * NN + ti * TN + c4 * 16) = z;
      return;
    }
  }

  f32x4 acc[2][2] = {};
  int rl = lane & 15, kg = lane >> 4;
  for (int step = 0; step < 8; ++step) {
    int k0 = step * BK;
    // stage A,B K-panels: wave w DMAs groups q=2w,2w+1 (8 rows x 128B each), LDS linear.
#pragma unroll
    for (int i = 0; i < 2; ++i) {
      int q = w * 2 + i;
      int r = q * 8 + lr;
      int cs = lc ^ (r & 7);  // pre-swizzled source chunk
      __builtin_amdgcn_global_load_lds(
          (const __attribute__((address_space(1))) unsigned int*)(Abase + (size_t)r * 512 + k0 + cs * 8),
          (__attribute__((address_space(3))) unsigned int*)(As + q * 512), 16, 0, 0);
      __builtin_amdgcn_global_load_lds(
          (const __attribute__((address_space(1))) unsigned int*)(Bbase + (size_t)r * 512 + k0 + cs * 8),
          (__attribute__((address_space(3))) unsigned int*)(Bs + q * 512), 16, 0, 0);
    }
    __syncthreads();  // drains vmcnt -> staged data visible
#pragma unroll
    for (int ks = 0; ks < 2; ++ks) {
      bf16x8 af[2], bq[2];
#pragma unroll
      for (int f = 0; f < 2; ++f) {
        int rA = wr * 32 + f * 16 + rl;
        af[f] = *(const bf16x8*)(&As[rA * BK + (((ks * 4 + kg) ^ (rA & 7)) << 3)]);
        int rB = wc * 32 + f * 16 + rl;
        bq[f] = *(const bf16x8*)(&Bs[rB * BK + (((ks * 4 + kg) ^ (rB & 7)) << 3)]);
      }
#pragma unroll
      for (int a = 0; a < 2; ++a)
#pragma unroll
        for (int b = 0; b < 2; ++b)
          acc[a][b] = __builtin_amdgcn_mfma_f32_16x16x32_bf16(af[a], bq[b], acc[a][b], 0, 0, 0);
    }
    __syncthreads();  // all reads done before next overwrite
  }
  // C/D layout: col = lane&15, row = (lane>>4)*4 + reg   [m89/m91 verified]
  int rbase = ti * TN + wr * 32 + ((lane >> 4) << 2);
  int cbase = tj * TN + wc * 32 + (lane & 15);
  if (!MASK) {
    float lm = -1e30f, lmin = 1e30f;
#pragma unroll
    for (int a = 0; a < 2; ++a) {
      float si[4];
#pragma unroll
      for (int r = 0; r < 4; ++r) si[r] = sqv[rbase + a * 16 + r];
#pragma unroll
      for (int b = 0; b < 2; ++b) {
        int gj = cbase + b * 16;
        float sj = sqv[gj];
#pragma unroll
        for (int r = 0; r < 4; ++r) {
          float d2v = si[r] - 2.f * acc[a][b][r] + sj;
          lm = fmaxf(lm, d2v);
          if (rbase + a * 16 + r < gj) lmin = fminf(lmin, d2v);
        }
      }
    }
#pragma unroll
    for (int o = 32; o > 0; o >>= 1) {
      lm = fmaxf(lm, __shfl_xor(lm, o));
      lmin = fminf(lmin, __shfl_xor(lmin, o));
    }
    if (lane == 0) { atomicMax(dmax, encf(lm)); wmin[w] = lmin; }
    __syncthreads();
    if (t == 0)
      tileMin[blockIdx.x] = fminf(fminf(wmin[0], wmin[1]), fminf(wmin[2], wmin[3]));
  } else {
#pragma unroll
    for (int b = 0; b < 2; ++b) {
      int gj = cbase + b * 16;
      float sj = sqv[gj];
#pragma unroll
      for (int a = 0; a < 2; ++a) {
        int gi0 = rbase + a * 16;
        union { unsigned char c[4]; unsigned u; } m4;
#pragma unroll
        for (int r = 0; r < 4; ++r) {
          float d2v = sqv[gi0 + r] - 2.f * acc[a][b][r] + sj;
          m4.c[r] = (d2v < thr && (gi0 + r) < gj) ? 1 : 0;
        }
        *(unsigned*)(ATm + (size_t)gj * NN + gi0) = m4.u;  // AT[j][i..i+3]
      }
    }
  }
}

// ---------- fp32 GEMM + row scale: C[i][c] = dinv[i] * (A@B)[i][c] ----------
__global__ __launch_bounds__(256) void k_gemm(const float* A, const float* B, const float* dinv,
                                              float* C, int M, int N, int K) {
  __shared__ float As[32][17];
  __shared__ float Bs[16][64];
  int t = threadIdx.x, tx = t & 15, ty = t >> 4;
  int nbx = N >> 6;
  int total = gridDim.x;
  int bid0 = blockIdx.x;
  int bid = (bid0 & 7) * (total >> 3) + (bid0 >> 3);  // bijective: total%8==0
  int m0 = (bid / nbx) * 32, n0 = (bid % nbx) * 64;
  int ar = t >> 3, ac = (t * 2) & 15;   // A stage: 2 floats/thread
  int br = t >> 4, bc = (t & 15) * 4;   // B stage: 4 floats/thread
  float2 ra = *(const float2*)(A + (size_t)(m0 + ar) * K + ac);
  float4 rb = *(const float4*)(B + (size_t)br * N + n0 + bc);
  float acc[2][4] = {};
  for (int k0 = 0; k0 < K; k0 += 16) {
    As[ar][ac] = ra.x; As[ar][ac + 1] = ra.y;
    *(float4*)(&Bs[br][bc]) = rb;
    __syncthreads();
    if (k0 + 16 < K) {  // prefetch next panel (overlaps compute)
      ra = *(const float2*)(A + (size_t)(m0 + ar) * K + k0 + 16 + ac);
      rb = *(const float4*)(B + (size_t)(k0 + 16 + br) * N + n0 + bc);
    }
#pragma unroll
    for (int kk = 0; kk < 16; ++kk) {
      float av[2], bv[4];
#pragma unroll
      for (int u = 0; u < 2; ++u) av[u] = As[ty * 2 + u][kk];
#pragma unroll
      for (int u = 0; u < 4; ++u) bv[u] = Bs[kk][tx * 4 + u];
#pragma unroll
      for (int a = 0; a < 2; ++a)
#pragma unroll
        for (int b2 = 0; b2 < 4; ++b2) acc[a][b2] = fmaf(av[a], bv[b2], acc[a][b2]);
    }
    __syncthreads();
  }
#pragma unroll
  for (int a = 0; a < 2; ++a) {
    float dv = dinv[m0 + ty * 2 + a];
#pragma unroll
    for (int b2 = 0; b2 < 4; ++b2)
      C[(size_t)(m0 + ty * 2 + a) * N + n0 + tx * 4 + b2] = acc[a][b2] * dv;
  }
}

// ---------- dinv[j] = 1/sqrt(1 + sum_i AT[j][i])  (layer 1 only) ----------
__global__ __launch_bounds__(256) void k_deg(const unsigned char* ATm, float* dinv, int n) {
  int w = threadIdx.x >> 6, lane = threadIdx.x & 63;
  int j = blockIdx.x * 4 + w;
  if (j >= n) return;
  const uint4* row = (const uint4*)(ATm + (size_t)j * n);
  int sum = 0;
  for (int p = lane; p < n / 16; p += 64) {
    uint4 v = row[p];
    unsigned a = v.x, b = v.y, c = v.z, d = v.w;
    sum += (a & 0xff) + ((a >> 8) & 0xff) + ((a >> 16) & 0xff) + (a >> 24);
    sum += (b & 0xff) + ((b >> 8) & 0xff) + ((b >> 16) & 0xff) + (b >> 24);
    sum += (c & 0xff) + ((c >> 8) & 0xff) + ((c >> 16) & 0xff) + (c >> 24);
    sum += (d & 0xff) + ((d >> 8) & 0xff) + ((d >> 16) & 0xff) + (d >> 24);
  }
  for (int s = 32; s > 0; s >>= 1) sum += __shfl_down(sum, s);
  if (lane == 0) dinv[j] = 1.f / sqrtf((float)(1 + sum));
}

// ---------- fused: xg row + relu + y2[j] = dinv[j]*dot(xg[j], Wpool) ----------
__global__ __launch_bounds__(256) void k_agg(const float* y, const unsigned char* ATm,
                                             const float* dinv, const float* bias,
                                             const float* Wpool, float* out, float* y2, int n) {
  __shared__ unsigned char mrow[256];
  __shared__ int s_any;
  __shared__ float red[256];
  int j = blockIdx.x, t = threadIdx.x;
  float acc = y[(size_t)j * 256 + t];
  for (int i0 = 0; i0 < n; i0 += 256) {
    if (t == 0) s_any = 0;
    __syncthreads();
    unsigned char m = ATm[(size_t)j * n + i0 + t];
    mrow[t] = m;
    if (m) s_any = 1;
    __syncthreads();
    if (s_any) {
      for (int u = 0; u < 256; ++u)
        if (mrow[u]) acc += y[(size_t)(i0 + u) * 256 + t];
    }
    __syncthreads();
  }
  float o = fmaxf(dinv[j] * acc + bias[t], 0.f);
  out[(size_t)j * 256 + t] = o;
  red[t] = o * Wpool[t]; __syncthreads();
  for (int s = 128; s > 0; s >>= 1) { if (t < s) red[t] += red[t + s]; __syncthreads(); }
  if (t == 0) y2[j] = dinv[j] * red[0];
}

// ---------- score[j] = tanh(dinv[j]*(y2[j] + sum_{i:AT[j,i]} y2[i]) + bpool) ----------
__global__ __launch_bounds__(256) void k_scorek(const float* y2, const unsigned char* ATm,
                                                const float* dinv, const float* bp,
                                                float* score, int n) {
  int w = threadIdx.x >> 6, lane = threadIdx.x & 63;
  int j = blockIdx.x * 4 + w;
  if (j >= n) return;
  const uint4* row = (const uint4*)(ATm + (size_t)j * n);
  float s = 0.f;
  for (int p = lane; p < n / 16; p += 64) {
    uint4 v = row[p];
    if (v.x | v.y | v.z | v.w) {
      int base = p * 16;
#pragma unroll
      for (int q = 0; q < 4; ++q) {
        unsigned u = (&v.x)[q];
#pragma unroll
        for (int b2 = 0; b2 < 4; ++b2)
          if ((u >> (8 * b2)) & 0xffu) s += y2[base + q * 4 + b2];
      }
    }
  }
  for (int sh = 32; sh > 0; sh >>= 1) s += __shfl_down(s, sh);
  if (lane == 0) score[j] = tanhf(dinv[j] * (y2[j] + s) + bp[0]);
}

// ---------- radix-select top-k (exact PyG set semantics; output in index order) ----------
__global__ __launch_bounds__(1024) void k_topsel(const float* score, int n, int k,
                                                 int* perm, float* vals) {
  __shared__ unsigned keys[4096];
  __shared__ unsigned hist[256];
  __shared__ unsigned s_state[2];  // [0]=prefix(cutoff), [1]=need(ties to take)
  __shared__ unsigned woff[16];
  int t = threadIdx.x, lane = t & 63, w = t >> 6;
  for (int i = t; i < 4096; i += 1024) keys[i] = (i < n) ? encf(score[i]) : 0u;
  if (t == 0) { s_state[0] = 0u; s_state[1] = (unsigned)k; }
  __syncthreads();

  for (int pass = 0; pass < 4; ++pass) {
    int shift = 24 - pass * 8;
    if (t < 256) hist[t] = 0u;
    __syncthreads();
    unsigned prefix = s_state[0];
    unsigned need = s_state[1];
    unsigned pmask = pass ? (0xFFFFFFFFu << (shift + 8)) : 0u;
    for (int i = t; i < n; i += 1024) {
      unsigned kk = keys[i];
      if ((kk & pmask) == prefix) atomicAdd(&hist[(kk >> shift) & 255u], 1u);
    }
    __syncthreads();
    if (w == 0) {
      unsigned h[4], suf[4];
#pragma unroll
      for (int r = 0; r < 4; ++r) h[r] = hist[lane * 4 + r];
      suf[3] = h[3]; suf[2] = h[2] + suf[3]; suf[1] = h[1] + suf[2]; suf[0] = h[0] + suf[1];
      unsigned lsum = suf[0];
      unsigned s = lsum;
#pragma unroll
      for (int off = 1; off < 64; off <<= 1) {
        unsigned o = __shfl_down(s, off);
        if (lane + off < 64) s += o;
      }
      unsigned Hl = s - lsum;
      int cand = -1; unsigned cumAt = 0, histAt = 0;
#pragma unroll
      for (int r = 0; r < 4; ++r) {
        unsigned c = Hl + suf[r];
        if (c >= need) { cand = lane * 4 + r; cumAt = c; histAt = h[r]; }
      }
      int gmax = cand;
#pragma unroll
      for (int off = 32; off > 0; off >>= 1) {
        int o = __shfl_xor(gmax, off);
        gmax = o > gmax ? o : gmax;
      }
      if (cand == gmax && cand >= 0) {
        s_state[0] = prefix | ((unsigned)cand << shift);
        s_state[1] = need - (cumAt - histAt);
      }
    }
    __syncthreads();
  }
  unsigned cutoff = s_state[0];
  unsigned tcount = s_state[1];
  unsigned G = (unsigned)k - tcount;

  int i0 = t * 4;
  unsigned loc[4], cnt = 0;
#pragma unroll
  for (int r = 0; r < 4; ++r) {
    unsigned kk = keys[i0 + r];
    unsigned g = (kk > cutoff) ? 1u : 0u;
    unsigned e = (kk == cutoff) ? 1u : 0u;
    loc[r] = cnt;
    cnt += (g << 16) | e;
  }
  unsigned inc = cnt;
#pragma unroll
  for (int off = 1; off < 64; off <<= 1) {
    unsigned o = __shfl_up(inc, off);
    if (lane >= off) inc += o;
  }
  if (lane == 63) woff[w] = inc;
  __syncthreads();
  if (t == 0) {
    unsigned run = 0;
    for (int q = 0; q < 16; ++q) { unsigned v = woff[q]; woff[q] = run; run += v; }
  }
  __syncthreads();
  unsigned base = woff[w] + (inc - cnt);
#pragma unroll
  for (int r = 0; r < 4; ++r) {
    unsigned kk = keys[i0 + r];
    unsigned p = base + loc[r];
    if (kk > cutoff) {
      unsigned pos = p >> 16;
      perm[pos] = i0 + r; vals[pos] = decf(kk);
    } else if (kk == cutoff) {
      unsigned pe = p & 0xffffu;
      if (pe < tcount) { perm[G + pe] = i0 + r; vals[G + pe] = decf(kk); }
    }
  }
}

// ---------- fused gather + readout partials: xp[r] = xg[perm[r]]*vals[r]; max/sum ----------
__global__ __launch_bounds__(256) void k_gxp(const float* xg, const int* perm, const float* vals,
                                             float* xp, float* pmax, float* psum, int k) {
  int b = blockIdx.x, t = threadIdx.x;
  float m = -1e30f, s = 0.f;
  for (int r = b; r < k; r += RB) {
    float v = xg[(size_t)perm[r] * 256 + t] * vals[r];
    xp[(size_t)r * 256 + t] = v;
    m = fmaxf(m, v); s += v;
  }
  pmax[b * 256 + t] = m; psum[b * 256 + t] = s;
}
__global__ void k_rfin(const float* pmax, const float* psum, float* out, int k) {
  int t = threadIdx.x;
  float m = -1e30f, s = 0.f;
  for (int q = 0; q < RB; ++q) { m = fmaxf(m, pmax[q * 256 + t]); s += psum[q * 256 + t]; }
  out[t] += m;
  out[256 + t] += s / (float)k;
}

// ---------- ATnew[c][r] = ATold[perm[c]][perm[r]]  + fused deg for next layer ----------
__global__ __launch_bounds__(256) void k_gatherA(const unsigned char* ATold, const int* perm,
                                                 unsigned char* ATnew, float* dinvNext,
                                                 int nold, int kn) {
  __shared__ int sperm[4096];
  __shared__ int redi[256];
  int t = threadIdx.x, c = blockIdx.x;
  for (int r = t; r < kn; r += 256) sperm[r] = perm[r];
  __syncthreads();
  const unsigned char* row = ATold + (size_t)sperm[c] * nold;
  unsigned char* orow = ATnew + (size_t)c * kn;
  int cnt = 0;
  for (int r = t; r < kn; r += 256) { unsigned char v = row[sperm[r]]; orow[r] = v; cnt += v; }
  redi[t] = cnt; __syncthreads();
  for (int s = 128; s > 0; s >>= 1) { if (t < s) redi[t] += redi[t + s]; __syncthreads(); }
  if (t == 0) dinvNext[c] = 1.f / sqrtf((float)(1 + redi[0]));
}

// ---------- host-side layer driver ----------
static void run_layer(hipStream_t stream, const float* x_in, int n, int inC,
                      const float* W, const float* b, const float* Wpool, const float* bpool,
                      int k, const unsigned char* ATcur, unsigned char* ATnext,
                      const float* dinvCur, float* dinvNext,
                      float* ybuf, float* xg, float* xp, float* y2,
                      float* score, int* perm, float* vals, float* pmax, float* psum, float* out) {
  k_gemm<<<(n / 32) * 4, 256, 0, stream>>>(x_in, W, dinvCur, ybuf, n, 256, inC);
  k_agg<<<n, 256, 0, stream>>>(ybuf, ATcur, dinvCur, b, Wpool, xg, y2, n);
  k_scorek<<<n / 4, 256, 0, stream>>>(y2, ATcur, dinvCur, bpool, score, n);
  k_topsel<<<1, 1024, 0, stream>>>(score, n, k, perm, vals);
  k_gxp<<<RB, 256, 0, stream>>>(xg, perm, vals, xp, pmax, psum, k);
  k_rfin<<<1, 256, 0, stream>>>(pmax, psum, out, k);
  if (ATnext) k_gatherA<<<k, 256, 0, stream>>>(ATcur, perm, ATnext, dinvNext, n, k);
}

extern "C" void kernel_launch(void* const* d_in, const int* in_sizes, int n_in,
                              void* d_out, int out_size, void* d_ws, size_t ws_size,
                              hipStream_t stream) {
  const float* feature = (const float*)d_in[0];
  const float* img     = (const float*)d_in[1];
  const float* Wp      = (const float*)d_in[2];
  const float* bp      = (const float*)d_in[3];
  const float* ln_f_g  = (const float*)d_in[4];
  const float* ln_f_b  = (const float*)d_in[5];
  const float* ln_p_g  = (const float*)d_in[6];
  const float* ln_p_b  = (const float*)d_in[7];
  const float* W1 = (const float*)d_in[8];   const float* b1 = (const float*)d_in[9];
  const float* Wpool1 = (const float*)d_in[10]; const float* bpool1 = (const float*)d_in[11];
  const float* W2 = (const float*)d_in[12];  const float* b2 = (const float*)d_in[13];
  const float* Wpool2 = (const float*)d_in[14]; const float* bpool2 = (const float*)d_in[15];
  const float* W3 = (const float*)d_in[16];  const float* b3 = (const float*)d_in[17];
  const float* Wpool3 = (const float*)d_in[18]; const float* bpool3 = (const float*)d_in[19];
  float* out = (float*)d_out;
  (void)in_sizes; (void)n_in; (void)out_size; (void)ws_size;

  char* w = (char*)d_ws;
  size_t off = 0;
  auto alloc = [&](size_t bytes) -> char* {
    off = (off + 255) & ~(size_t)255;
    char* p = w + off;
    off += bytes;
    return p;
  };
  float* pos0 = (float*)alloc((size_t)NN * 12 * 4);
  float* pos1 = (float*)alloc((size_t)NN * 12 * 4);
  float* x0   = (float*)alloc((size_t)NN * 512 * 4);
  unsigned short* x0h = (unsigned short*)alloc((size_t)NN * 512 * 2);
  float* sqv  = (float*)alloc((size_t)NN * 4);
  unsigned* dmax = (unsigned*)alloc(4);
  float* tileMin = (float*)alloc(2080 * 4);
  float* dinvA = (float*)alloc((size_t)NN * 4);
  float* dinvB = (float*)alloc((size_t)NN * 4);
  float* ybuf = (float*)alloc((size_t)NN * 256 * 4);
  float* xg   = (float*)alloc((size_t)NN * 256 * 4);
  float* xp   = (float*)alloc((size_t)NN * 256 * 4);
  float* y2   = (float*)alloc((size_t)NN * 4);
  float* score= (float*)alloc((size_t)NN * 4);
  int*   perm = (int*)alloc((size_t)NN * 4);
  float* vals = (float*)alloc((size_t)NN * 4);
  float* pmax = (float*)alloc(RB * 256 * 4);
  float* psum = (float*)alloc(RB * 256 * 4);
  unsigned char* ATa = (unsigned char*)alloc((size_t)NN * NN);
  unsigned char* ATb = (unsigned char*)alloc((size_t)3072 * 3072);

  // preamble
  k_init<<<2, 256, 0, stream>>>(out, dmax);
  k_pos<<<(NN * 12 + 255) / 256, 256, 0, stream>>>(img, Wp, bp, pos0);
  k_attn3<<<NN / 8, 256, 0, stream>>>(pos0, pos1);
  k_lnx<<<NN, 256, 0, stream>>>(feature, ln_f_g, ln_f_b, pos1, ln_p_g, ln_p_b, x0, x0h, sqv);

  // edge construction via MFMA: max+tileMin pass, then pruned mask pass (no memset)
  const int NT = NN / TN, TT = NT * (NT + 1) / 2;  // 64, 2080
  k_d2m<false><<<TT, 256, 0, stream>>>(x0h, sqv, dmax, tileMin, nullptr);
  k_d2m<true><<<TT, 256, 0, stream>>>(x0h, sqv, dmax, tileMin, ATa);

  // layer-1 degree (layers 2-3 get dinv from fused gatherA)
  k_deg<<<NN / 4, 256, 0, stream>>>(ATa, dinvA, NN);

  // three GCN + SAGPool + readout layers
  run_layer(stream, x0, 4096, 512, W1, b1, Wpool1, bpool1, 3072, ATa, ATb, dinvA, dinvB,
            ybuf, xg, xp, y2, score, perm, vals, pmax, psum, out);
  run_layer(stream, xp, 3072, 256, W2, b2, Wpool2, bpool2, 2304, ATb, ATa, dinvB, dinvA,
            ybuf, xg, xp, y2, score, perm, vals, pmax, psum, out);
  run_layer(stream, xp, 2304, 256, W3, b3, Wpool3, bpool3, 1728, ATa, nullptr, dinvA, nullptr,
            ybuf, xg, xp, y2, score, perm, vals, pmax, psum, out);
}

// Round 12
// 287.369 us; speedup vs baseline: 1.3001x; 1.3001x over previous
//
#include <hip/hip_runtime.h>
#include <math.h>

#define NN 4096
#define RB 128  // readout stage-1 blocks

typedef __attribute__((ext_vector_type(8))) short bf16x8;
typedef __attribute__((ext_vector_type(4))) float f32x4;

// ---------- helpers ----------
__device__ __forceinline__ unsigned encf(float f) {
  unsigned u = __float_as_uint(f);
  return (u & 0x80000000u) ? ~u : (u | 0x80000000u);
}
__device__ __forceinline__ float decf(unsigned u) {
  return __uint_as_float((u & 0x80000000u) ? (u ^ 0x80000000u) : ~u);
}
__device__ __forceinline__ unsigned short f2bf(float f) {
  unsigned u = __float_as_uint(f);
  return (unsigned short)((u + 0x7fffu + ((u >> 16) & 1u)) >> 16);
}

// ---------- init ----------
__global__ void k_init(float* out, unsigned* dmax) {
  int t = blockIdx.x * 256 + threadIdx.x;
  if (t < 512) out[t] = 0.f;
  if (t == 0) *dmax = 0u;
}

// ---------- pos = img @ Wp + bp ----------
__global__ void k_pos(const float* img, const float* Wp, const float* bp, float* pos) {
  int t = blockIdx.x * 256 + threadIdx.x;
  if (t >= NN * 12) return;
  int i = t / 12, d = t % 12;
  float s = bp[d];
#pragma unroll
  for (int k = 0; k < 6; ++k) s += img[i * 6 + k] * Wp[k * 12 + d];
  pos[t] = s;
}

// ---------- attention, d=12, LDS-tiled keys, branch-free softmax ----------
__global__ __launch_bounds__(256) void k_attn3(const float* pos, float* out) {
  __shared__ float sp[12][256];
  int t = threadIdx.x, lane = t & 63, w = t >> 6;
  int ib = blockIdx.x * 8 + w * 2;  // 2 rows per wave, 8 per block
  float pi[2][12];
#pragma unroll
  for (int r = 0; r < 2; ++r)
#pragma unroll
    for (int d = 0; d < 12; ++d) pi[r][d] = pos[(ib + r) * 12 + d] * 0.28867513459481287f;
  float sl[2] = {0.f, 0.f};
  float acc[2][12] = {};
  const float4* p4 = (const float4*)pos;
  for (int kt = 0; kt < NN; kt += 256) {
    __syncthreads();  // previous tile fully consumed
    int j = kt + t;
    float4 a = p4[j * 3 + 0], b = p4[j * 3 + 1], c = p4[j * 3 + 2];
    sp[0][t] = a.x; sp[1][t] = a.y; sp[2][t] = a.z; sp[3][t] = a.w;
    sp[4][t] = b.x; sp[5][t] = b.y; sp[6][t] = b.z; sp[7][t] = b.w;
    sp[8][t] = c.x; sp[9][t] = c.y; sp[10][t] = c.z; sp[11][t] = c.w;
    __syncthreads();
#pragma unroll
    for (int q = 0; q < 4; ++q) {
      int jj = q * 64 + lane;
      float pj[12];
#pragma unroll
      for (int d = 0; d < 12; ++d) pj[d] = sp[d][jj];
#pragma unroll
      for (int r = 0; r < 2; ++r) {
        float s = 0.f;
#pragma unroll
        for (int d = 0; d < 12; ++d) s = fmaf(pi[r][d], pj[d], s);
        float e = __expf(s);
        sl[r] += e;
#pragma unroll
        for (int d = 0; d < 12; ++d) acc[r][d] = fmaf(e, pj[d], acc[r][d]);
      }
    }
  }
#pragma unroll
  for (int r = 0; r < 2; ++r) {
    float s = sl[r];
#pragma unroll
    for (int o = 32; o > 0; o >>= 1) s += __shfl_xor(s, o);
    float ad[12];
#pragma unroll
    for (int d = 0; d < 12; ++d) {
      ad[d] = acc[r][d];
#pragma unroll
      for (int o = 32; o > 0; o >>= 1) ad[d] += __shfl_xor(ad[d], o);
    }
    if (lane == 0) {
      float inv = 1.f / s;
#pragma unroll
      for (int d = 0; d < 12; ++d) out[(ib + r) * 12 + d] = ad[d] * inv;
    }
  }
}

// ---------- fused layernorms + sumsq + bf16 convert ----------
__global__ __launch_bounds__(256) void k_lnx(const float* f, const float* g, const float* b,
                                             const float* p, const float* pg, const float* pb,
                                             float* x0, unsigned short* x0h, float* sqv) {
  __shared__ float row[512];
  __shared__ float red[256];
  int i = blockIdx.x, t = threadIdx.x;
  float v1 = f[i * 500 + t];
  float v2 = (t < 244) ? f[i * 500 + 256 + t] : 0.f;
  red[t] = v1 + v2; __syncthreads();
  for (int s = 128; s > 0; s >>= 1) { if (t < s) red[t] += red[t + s]; __syncthreads(); }
  float m = red[0] * (1.f / 500.f); __syncthreads();
  float d1 = v1 - m, d2 = v2 - m;
  red[t] = d1 * d1 + ((t < 244) ? d2 * d2 : 0.f); __syncthreads();
  for (int s = 128; s > 0; s >>= 1) { if (t < s) red[t] += red[t + s]; __syncthreads(); }
  float scale = 1.f / sqrtf(red[0] * (1.f / 500.f) + 1e-5f);
  row[t] = d1 * scale * g[t] + b[t];
  if (t < 244) row[256 + t] = d2 * scale * g[256 + t] + b[256 + t];
  if (t >= 244) {  // threads 244..255 handle the 12-wide pos layernorm
    int tt = t - 244;
    float pv[12], pm = 0.f;
#pragma unroll
    for (int d = 0; d < 12; ++d) { pv[d] = p[i * 12 + d]; pm += pv[d]; }
    pm *= (1.f / 12.f);
    float pvar = 0.f;
#pragma unroll
    for (int d = 0; d < 12; ++d) { float dd = pv[d] - pm; pvar += dd * dd; }
    pvar *= (1.f / 12.f);
    float ps = 1.f / sqrtf(pvar + 1e-5f);
    row[500 + tt] = (pv[tt] - pm) * ps * pg[tt] + pb[tt];
  }
  __syncthreads();
  float a = row[t], c = row[256 + t];
  red[t] = a * a + c * c; __syncthreads();
  for (int s = 128; s > 0; s >>= 1) { if (t < s) red[t] += red[t + s]; __syncthreads(); }
  if (t == 0) sqv[i] = red[0];
  x0[(size_t)i * 512 + t] = a;
  x0[(size_t)i * 512 + 256 + t] = c;
  x0h[(size_t)i * 512 + t] = f2bf(a);
  x0h[(size_t)i * 512 + 256 + t] = f2bf(c);
}

// ---------- MFMA d2 tiles (128x128, upper tile pairs): max / mask pass ----------
// T4 pipeline (m201 pattern): double-buffered LDS; issue next panel's 8 DMAs, then
// COUNTED s_waitcnt vmcnt(8) (waits for current panel only; next stays in flight),
// sched_barrier(0) fence (rule #18), raw s_barrier. Second raw barrier after MFMAs
// guards buffer reuse. No vmcnt(0) drain in the loop body (the R5-R11 serializer).
// Source pre-swizzled (chunk = (lane&7)^(row&7)); reads apply the same XOR.
// Pass A records per-tile min over gi<gj; pass B skips GEMM when tileMin >= thr and
// zeroes mirror tiles -> no memset.
#define BK 64
template <bool MASK>
__global__ __launch_bounds__(256) void k_d2m(const unsigned short* X, const float* sqv,
                                             unsigned* dmax, float* tileMin,
                                             unsigned char* ATm) {
  __shared__ unsigned short As[2][128 * BK];
  __shared__ unsigned short Bs[2][128 * BK];
  __shared__ float wmax[4], wmin[4];
  const int NT = NN / 128;
  int bid0 = blockIdx.x;
  int bid = (bid0 & 7) * 66 + (bid0 >> 3);  // 528 total, bijective
  int ti = 0, rem = bid;
  while (rem >= NT - ti) { rem -= NT - ti; ++ti; }
  int tj = ti + rem;
  int t = threadIdx.x, lane = t & 63, w = t >> 6;
  int wr = w >> 1, wc = w & 1;  // wave's 64x64 sub-tile
  const unsigned short* Abase = X + (size_t)ti * 128 * 512;
  const unsigned short* Bbase = X + (size_t)tj * 128 * 512;
  int lr = lane >> 3, lc = lane & 7;

  float thr = 0.f;
  if (MASK) {
    thr = 0.5f * decf(*dmax);
    uint4 z = make_uint4(0u, 0u, 0u, 0u);
    if (ti != tj) {  // mirror tile (rows ti, cols tj) never receives mask writes
#pragma unroll
      for (int q0 = 0; q0 < 4; ++q0) {
        int q = t + q0 * 256; int r = q >> 3, c4 = q & 7;
        *(uint4*)(ATm + (size_t)(ti * 128 + r) * NN + tj * 128 + c4 * 16) = z;
      }
    }
    if (tileMin[blockIdx.x] >= thr) {  // no element can pass -> zero tile, skip GEMM
#pragma unroll
      for (int q0 = 0; q0 < 4; ++q0) {
        int q = t + q0 * 256; int r = q >> 3, c4 = q & 7;
        *(uint4*)(ATm + (size_t)(tj * 128 + r) * NN + ti * 128 + c4 * 16) = z;
      }
      return;
    }
  }

  auto stage = [&](int buf, int k0) {  // 8 DMAs per wave (4x A + 4x B)
#pragma unroll
    for (int i = 0; i < 4; ++i) {
      int q = w * 4 + i;
      int r = q * 8 + lr;
      int cs = lc ^ (r & 7);  // pre-swizzled source chunk
      __builtin_amdgcn_global_load_lds(
          (const __attribute__((address_space(1))) unsigned int*)(Abase + (size_t)r * 512 + k0 + cs * 8),
          (__attribute__((address_space(3))) unsigned int*)(&As[buf][q * 512]), 16, 0, 0);
      __builtin_amdgcn_global_load_lds(
          (const __attribute__((address_space(1))) unsigned int*)(Bbase + (size_t)r * 512 + k0 + cs * 8),
          (__attribute__((address_space(3))) unsigned int*)(&Bs[buf][q * 512]), 16, 0, 0);
    }
  };

  stage(0, 0);  // 8 outstanding

  f32x4 acc[4][4] = {};
  int rl = lane & 15, kg = lane >> 4;
  for (int step = 0; step < 8; ++step) {
    int cur = step & 1;
    if (step < 7) {
      stage(cur ^ 1, (step + 1) * BK);  // +8 in flight (16 total)
      asm volatile("s_waitcnt vmcnt(8)" ::: "memory");  // cur's 8 retired (in-order)
    } else {
      asm volatile("s_waitcnt vmcnt(0)" ::: "memory");
    }
    __builtin_amdgcn_sched_barrier(0);
    __builtin_amdgcn_s_barrier();  // all waves' cur panel visible
#pragma unroll
    for (int ks = 0; ks < 2; ++ks) {
      bf16x8 af[4], bq[4];
#pragma unroll
      for (int f = 0; f < 4; ++f) {
        int rA = wr * 64 + f * 16 + rl;
        af[f] = *(const bf16x8*)(&As[cur][rA * BK + (((ks * 4 + kg) ^ (rA & 7)) << 3)]);
        int rB = wc * 64 + f * 16 + rl;
        bq[f] = *(const bf16x8*)(&Bs[cur][rB * BK + (((ks * 4 + kg) ^ (rB & 7)) << 3)]);
      }
#pragma unroll
      for (int a = 0; a < 4; ++a)
#pragma unroll
        for (int b = 0; b < 4; ++b)
          acc[a][b] = __builtin_amdgcn_mfma_f32_16x16x32_bf16(af[a], bq[b], acc[a][b], 0, 0, 0);
    }
    __builtin_amdgcn_sched_barrier(0);  // pin ds_reads before the reuse barrier
    __builtin_amdgcn_s_barrier();       // all reads of cur done before its overwrite
  }
  // C/D layout: col = lane&15, row = (lane>>4)*4 + reg   [m89/m91 verified]
  int rbase = ti * 128 + wr * 64 + ((lane >> 4) << 2);
  int cbase = tj * 128 + wc * 64 + (lane & 15);
  if (!MASK) {
    float lm = -1e30f, lmin = 1e30f;
#pragma unroll
    for (int a = 0; a < 4; ++a) {
      float si[4];
#pragma unroll
      for (int r = 0; r < 4; ++r) si[r] = sqv[rbase + a * 16 + r];
#pragma unroll
      for (int b = 0; b < 4; ++b) {
        int gj = cbase + b * 16;
        float sj = sqv[gj];
#pragma unroll
        for (int r = 0; r < 4; ++r) {
          float d2v = si[r] - 2.f * acc[a][b][r] + sj;
          lm = fmaxf(lm, d2v);
          if (rbase + a * 16 + r < gj) lmin = fminf(lmin, d2v);
        }
      }
    }
#pragma unroll
    for (int o = 32; o > 0; o >>= 1) {
      lm = fmaxf(lm, __shfl_xor(lm, o));
      lmin = fminf(lmin, __shfl_xor(lmin, o));
    }
    if (lane == 0) { wmax[w] = lm; wmin[w] = lmin; }
    __syncthreads();
    if (t == 0) {
      atomicMax(dmax, encf(fmaxf(fmaxf(wmax[0], wmax[1]), fmaxf(wmax[2], wmax[3]))));
      tileMin[blockIdx.x] = fminf(fminf(wmin[0], wmin[1]), fminf(wmin[2], wmin[3]));
    }
  } else {
#pragma unroll
    for (int b = 0; b < 4; ++b) {
      int gj = cbase + b * 16;
      float sj = sqv[gj];
#pragma unroll
      for (int a = 0; a < 4; ++a) {
        int gi0 = rbase + a * 16;
        union { unsigned char c[4]; unsigned u; } m4;
#pragma unroll
        for (int r = 0; r < 4; ++r) {
          float d2v = sqv[gi0 + r] - 2.f * acc[a][b][r] + sj;
          m4.c[r] = (d2v < thr && (gi0 + r) < gj) ? 1 : 0;
        }
        *(unsigned*)(ATm + (size_t)gj * NN + gi0) = m4.u;  // AT[j][i..i+3]
      }
    }
  }
}

// ---------- fp32 GEMM + row scale: C[i][c] = dinv[i] * (A@B)[i][c] ----------
__global__ __launch_bounds__(256) void k_gemm(const float* A, const float* B, const float* dinv,
                                              float* C, int M, int N, int K) {
  __shared__ float As[32][17];
  __shared__ float Bs[16][64];
  int t = threadIdx.x, tx = t & 15, ty = t >> 4;
  int nbx = N >> 6;
  int total = gridDim.x;
  int bid0 = blockIdx.x;
  int bid = (bid0 & 7) * (total >> 3) + (bid0 >> 3);  // bijective: total%8==0
  int m0 = (bid / nbx) * 32, n0 = (bid % nbx) * 64;
  int ar = t >> 3, ac = (t * 2) & 15;   // A stage: 2 floats/thread
  int br = t >> 4, bc = (t & 15) * 4;   // B stage: 4 floats/thread
  float2 ra = *(const float2*)(A + (size_t)(m0 + ar) * K + ac);
  float4 rb = *(const float4*)(B + (size_t)br * N + n0 + bc);
  float acc[2][4] = {};
  for (int k0 = 0; k0 < K; k0 += 16) {
    As[ar][ac] = ra.x; As[ar][ac + 1] = ra.y;
    *(float4*)(&Bs[br][bc]) = rb;
    __syncthreads();
    if (k0 + 16 < K) {  // prefetch next panel (overlaps compute)
      ra = *(const float2*)(A + (size_t)(m0 + ar) * K + k0 + 16 + ac);
      rb = *(const float4*)(B + (size_t)(k0 + 16 + br) * N + n0 + bc);
    }
#pragma unroll
    for (int kk = 0; kk < 16; ++kk) {
      float av[2], bv[4];
#pragma unroll
      for (int u = 0; u < 2; ++u) av[u] = As[ty * 2 + u][kk];
#pragma unroll
      for (int u = 0; u < 4; ++u) bv[u] = Bs[kk][tx * 4 + u];
#pragma unroll
      for (int a = 0; a < 2; ++a)
#pragma unroll
        for (int b2 = 0; b2 < 4; ++b2) acc[a][b2] = fmaf(av[a], bv[b2], acc[a][b2]);
    }
    __syncthreads();
  }
#pragma unroll
  for (int a = 0; a < 2; ++a) {
    float dv = dinv[m0 + ty * 2 + a];
#pragma unroll
    for (int b2 = 0; b2 < 4; ++b2)
      C[(size_t)(m0 + ty * 2 + a) * N + n0 + tx * 4 + b2] = acc[a][b2] * dv;
  }
}

// ---------- dinv[j] = 1/sqrt(1 + sum_i AT[j][i])  (layer 1 only) ----------
__global__ __launch_bounds__(256) void k_deg(const unsigned char* ATm, float* dinv, int n) {
  int w = threadIdx.x >> 6, lane = threadIdx.x & 63;
  int j = blockIdx.x * 4 + w;
  if (j >= n) return;
  const uint4* row = (const uint4*)(ATm + (size_t)j * n);
  int sum = 0;
  for (int p = lane; p < n / 16; p += 64) {
    uint4 v = row[p];
    unsigned a = v.x, b = v.y, c = v.z, d = v.w;
    sum += (a & 0xff) + ((a >> 8) & 0xff) + ((a >> 16) & 0xff) + (a >> 24);
    sum += (b & 0xff) + ((b >> 8) & 0xff) + ((b >> 16) & 0xff) + (b >> 24);
    sum += (c & 0xff) + ((c >> 8) & 0xff) + ((c >> 16) & 0xff) + (c >> 24);
    sum += (d & 0xff) + ((d >> 8) & 0xff) + ((d >> 16) & 0xff) + (d >> 24);
  }
  for (int s = 32; s > 0; s >>= 1) sum += __shfl_down(sum, s);
  if (lane == 0) dinv[j] = 1.f / sqrtf((float)(1 + sum));
}

// ---------- fused: xg row + relu + y2[j] = dinv[j]*dot(xg[j], Wpool) ----------
__global__ __launch_bounds__(256) void k_agg(const float* y, const unsigned char* ATm,
                                             const float* dinv, const float* bias,
                                             const float* Wpool, float* out, float* y2, int n) {
  __shared__ unsigned char mrow[256];
  __shared__ int s_any;
  __shared__ float red[256];
  int j = blockIdx.x, t = threadIdx.x;
  float acc = y[(size_t)j * 256 + t];
  for (int i0 = 0; i0 < n; i0 += 256) {
    if (t == 0) s_any = 0;
    __syncthreads();
    unsigned char m = ATm[(size_t)j * n + i0 + t];
    mrow[t] = m;
    if (m) s_any = 1;
    __syncthreads();
    if (s_any) {
      for (int u = 0; u < 256; ++u)
        if (mrow[u]) acc += y[(size_t)(i0 + u) * 256 + t];
    }
    __syncthreads();
  }
  float o = fmaxf(dinv[j] * acc + bias[t], 0.f);
  out[(size_t)j * 256 + t] = o;
  red[t] = o * Wpool[t]; __syncthreads();
  for (int s = 128; s > 0; s >>= 1) { if (t < s) red[t] += red[t + s]; __syncthreads(); }
  if (t == 0) y2[j] = dinv[j] * red[0];
}

// ---------- score[j] = tanh(dinv[j]*(y2[j] + sum_{i:AT[j,i]} y2[i]) + bpool) ----------
__global__ __launch_bounds__(256) void k_scorek(const float* y2, const unsigned char* ATm,
                                                const float* dinv, const float* bp,
                                                float* score, int n) {
  int w = threadIdx.x >> 6, lane = threadIdx.x & 63;
  int j = blockIdx.x * 4 + w;
  if (j >= n) return;
  const uint4* row = (const uint4*)(ATm + (size_t)j * n);
  float s = 0.f;
  for (int p = lane; p < n / 16; p += 64) {
    uint4 v = row[p];
    if (v.x | v.y | v.z | v.w) {
      int base = p * 16;
#pragma unroll
      for (int q = 0; q < 4; ++q) {
        unsigned u = (&v.x)[q];
#pragma unroll
        for (int b2 = 0; b2 < 4; ++b2)
          if ((u >> (8 * b2)) & 0xffu) s += y2[base + q * 4 + b2];
      }
    }
  }
  for (int sh = 32; sh > 0; sh >>= 1) s += __shfl_down(s, sh);
  if (lane == 0) score[j] = tanhf(dinv[j] * (y2[j] + s) + bp[0]);
}

// ---------- radix-select top-k (exact PyG set semantics; output in index order) ----------
__global__ __launch_bounds__(1024) void k_topsel(const float* score, int n, int k,
                                                 int* perm, float* vals) {
  __shared__ unsigned keys[4096];
  __shared__ unsigned hist[256];
  __shared__ unsigned s_state[2];  // [0]=prefix(cutoff), [1]=need(ties to take)
  __shared__ unsigned woff[16];
  int t = threadIdx.x, lane = t & 63, w = t >> 6;
  for (int i = t; i < 4096; i += 1024) keys[i] = (i < n) ? encf(score[i]) : 0u;
  if (t == 0) { s_state[0] = 0u; s_state[1] = (unsigned)k; }
  __syncthreads();

  for (int pass = 0; pass < 4; ++pass) {
    int shift = 24 - pass * 8;
    if (t < 256) hist[t] = 0u;
    __syncthreads();
    unsigned prefix = s_state[0];
    unsigned need = s_state[1];
    unsigned pmask = pass ? (0xFFFFFFFFu << (shift + 8)) : 0u;
    for (int i = t; i < n; i += 1024) {
      unsigned kk = keys[i];
      if ((kk & pmask) == prefix) atomicAdd(&hist[(kk >> shift) & 255u], 1u);
    }
    __syncthreads();
    if (w == 0) {
      unsigned h[4], suf[4];
#pragma unroll
      for (int r = 0; r < 4; ++r) h[r] = hist[lane * 4 + r];
      suf[3] = h[3]; suf[2] = h[2] + suf[3]; suf[1] = h[1] + suf[2]; suf[0] = h[0] + suf[1];
      unsigned lsum = suf[0];
      unsigned s = lsum;
#pragma unroll
      for (int off = 1; off < 64; off <<= 1) {
        unsigned o = __shfl_down(s, off);
        if (lane + off < 64) s += o;
      }
      unsigned Hl = s - lsum;
      int cand = -1; unsigned cumAt = 0, histAt = 0;
#pragma unroll
      for (int r = 0; r < 4; ++r) {
        unsigned c = Hl + suf[r];
        if (c >= need) { cand = lane * 4 + r; cumAt = c; histAt = h[r]; }
      }
      int gmax = cand;
#pragma unroll
      for (int off = 32; off > 0; off >>= 1) {
        int o = __shfl_xor(gmax, off);
        gmax = o > gmax ? o : gmax;
      }
      if (cand == gmax && cand >= 0) {
        s_state[0] = prefix | ((unsigned)cand << shift);
        s_state[1] = need - (cumAt - histAt);
      }
    }
    __syncthreads();
  }
  unsigned cutoff = s_state[0];
  unsigned tcount = s_state[1];
  unsigned G = (unsigned)k - tcount;

  int i0 = t * 4;
  unsigned loc[4], cnt = 0;
#pragma unroll
  for (int r = 0; r < 4; ++r) {
    unsigned kk = keys[i0 + r];
    unsigned g = (kk > cutoff) ? 1u : 0u;
    unsigned e = (kk == cutoff) ? 1u : 0u;
    loc[r] = cnt;
    cnt += (g << 16) | e;
  }
  unsigned inc = cnt;
#pragma unroll
  for (int off = 1; off < 64; off <<= 1) {
    unsigned o = __shfl_up(inc, off);
    if (lane >= off) inc += o;
  }
  if (lane == 63) woff[w] = inc;
  __syncthreads();
  if (t == 0) {
    unsigned run = 0;
    for (int q = 0; q < 16; ++q) { unsigned v = woff[q]; woff[q] = run; run += v; }
  }
  __syncthreads();
  unsigned base = woff[w] + (inc - cnt);
#pragma unroll
  for (int r = 0; r < 4; ++r) {
    unsigned kk = keys[i0 + r];
    unsigned p = base + loc[r];
    if (kk > cutoff) {
      unsigned pos = p >> 16;
      perm[pos] = i0 + r; vals[pos] = decf(kk);
    } else if (kk == cutoff) {
      unsigned pe = p & 0xffffu;
      if (pe < tcount) { perm[G + pe] = i0 + r; vals[G + pe] = decf(kk); }
    }
  }
}

// ---------- fused gather + readout partials: xp[r] = xg[perm[r]]*vals[r]; max/sum ----------
__global__ __launch_bounds__(256) void k_gxp(const float* xg, const int* perm, const float* vals,
                                             float* xp, float* pmax, float* psum, int k) {
  int b = blockIdx.x, t = threadIdx.x;
  float m = -1e30f, s = 0.f;
  for (int r = b; r < k; r += RB) {
    float v = xg[(size_t)perm[r] * 256 + t] * vals[r];
    xp[(size_t)r * 256 + t] = v;
    m = fmaxf(m, v); s += v;
  }
  pmax[b * 256 + t] = m; psum[b * 256 + t] = s;
}
__global__ void k_rfin(const float* pmax, const float* psum, float* out, int k) {
  int t = threadIdx.x;
  float m = -1e30f, s = 0.f;
  for (int q = 0; q < RB; ++q) { m = fmaxf(m, pmax[q * 256 + t]); s += psum[q * 256 + t]; }
  out[t] += m;
  out[256 + t] += s / (float)k;
}

// ---------- ATnew[c][r] = ATold[perm[c]][perm[r]]  + fused deg for next layer ----------
__global__ __launch_bounds__(256) void k_gatherA(const unsigned char* ATold, const int* perm,
                                                 unsigned char* ATnew, float* dinvNext,
                                                 int nold, int kn) {
  __shared__ int sperm[4096];
  __shared__ int redi[256];
  int t = threadIdx.x, c = blockIdx.x;
  for (int r = t; r < kn; r += 256) sperm[r] = perm[r];
  __syncthreads();
  const unsigned char* row = ATold + (size_t)sperm[c] * nold;
  unsigned char* orow = ATnew + (size_t)c * kn;
  int cnt = 0;
  for (int r = t; r < kn; r += 256) { unsigned char v = row[sperm[r]]; orow[r] = v; cnt += v; }
  redi[t] = cnt; __syncthreads();
  for (int s = 128; s > 0; s >>= 1) { if (t < s) redi[t] += redi[t + s]; __syncthreads(); }
  if (t == 0) dinvNext[c] = 1.f / sqrtf((float)(1 + redi[0]));
}

// ---------- host-side layer driver ----------
static void run_layer(hipStream_t stream, const float* x_in, int n, int inC,
                      const float* W, const float* b, const float* Wpool, const float* bpool,
                      int k, const unsigned char* ATcur, unsigned char* ATnext,
                      const float* dinvCur, float* dinvNext,
                      float* ybuf, float* xg, float* xp, float* y2,
                      float* score, int* perm, float* vals, float* pmax, float* psum, float* out) {
  k_gemm<<<(n / 32) * 4, 256, 0, stream>>>(x_in, W, dinvCur, ybuf, n, 256, inC);
  k_agg<<<n, 256, 0, stream>>>(ybuf, ATcur, dinvCur, b, Wpool, xg, y2, n);
  k_scorek<<<n / 4, 256, 0, stream>>>(y2, ATcur, dinvCur, bpool, score, n);
  k_topsel<<<1, 1024, 0, stream>>>(score, n, k, perm, vals);
  k_gxp<<<RB, 256, 0, stream>>>(xg, perm, vals, xp, pmax, psum, k);
  k_rfin<<<1, 256, 0, stream>>>(pmax, psum, out, k);
  if (ATnext) k_gatherA<<<k, 256, 0, stream>>>(ATcur, perm, ATnext, dinvNext, n, k);
}

extern "C" void kernel_launch(void* const* d_in, const int* in_sizes, int n_in,
                              void* d_out, int out_size, void* d_ws, size_t ws_size,
                              hipStream_t stream) {
  const float* feature = (const float*)d_in[0];
  const float* img     = (const float*)d_in[1];
  const float* Wp      = (const float*)d_in[2];
  const float* bp      = (const float*)d_in[3];
  const float* ln_f_g  = (const float*)d_in[4];
  const float* ln_f_b  = (const float*)d_in[5];
  const float* ln_p_g  = (const float*)d_in[6];
  const float* ln_p_b  = (const float*)d_in[7];
  const float* W1 = (const float*)d_in[8];   const float* b1 = (const float*)d_in[9];
  const float* Wpool1 = (const float*)d_in[10]; const float* bpool1 = (const float*)d_in[11];
  const float* W2 = (const float*)d_in[12];  const float* b2 = (const float*)d_in[13];
  const float* Wpool2 = (const float*)d_in[14]; const float* bpool2 = (const float*)d_in[15];
  const float* W3 = (const float*)d_in[16];  const float* b3 = (const float*)d_in[17];
  const float* Wpool3 = (const float*)d_in[18]; const float* bpool3 = (const float*)d_in[19];
  float* out = (float*)d_out;
  (void)in_sizes; (void)n_in; (void)out_size; (void)ws_size;

  char* w = (char*)d_ws;
  size_t off = 0;
  auto alloc = [&](size_t bytes) -> char* {
    off = (off + 255) & ~(size_t)255;
    char* p = w + off;
    off += bytes;
    return p;
  };
  float* pos0 = (float*)alloc((size_t)NN * 12 * 4);
  float* pos1 = (float*)alloc((size_t)NN * 12 * 4);
  float* x0   = (float*)alloc((size_t)NN * 512 * 4);
  unsigned short* x0h = (unsigned short*)alloc((size_t)NN * 512 * 2);
  float* sqv  = (float*)alloc((size_t)NN * 4);
  unsigned* dmax = (unsigned*)alloc(4);
  float* tileMin = (float*)alloc(528 * 4);
  float* dinvA = (float*)alloc((size_t)NN * 4);
  float* dinvB = (float*)alloc((size_t)NN * 4);
  float* ybuf = (float*)alloc((size_t)NN * 256 * 4);
  float* xg   = (float*)alloc((size_t)NN * 256 * 4);
  float* xp   = (float*)alloc((size_t)NN * 256 * 4);
  float* y2   = (float*)alloc((size_t)NN * 4);
  float* score= (float*)alloc((size_t)NN * 4);
  int*   perm = (int*)alloc((size_t)NN * 4);
  float* vals = (float*)alloc((size_t)NN * 4);
  float* pmax = (float*)alloc(RB * 256 * 4);
  float* psum = (float*)alloc(RB * 256 * 4);
  unsigned char* ATa = (unsigned char*)alloc((size_t)NN * NN);
  unsigned char* ATb = (unsigned char*)alloc((size_t)3072 * 3072);

  // preamble
  k_init<<<2, 256, 0, stream>>>(out, dmax);
  k_pos<<<(NN * 12 + 255) / 256, 256, 0, stream>>>(img, Wp, bp, pos0);
  k_attn3<<<NN / 8, 256, 0, stream>>>(pos0, pos1);
  k_lnx<<<NN, 256, 0, stream>>>(feature, ln_f_g, ln_f_b, pos1, ln_p_g, ln_p_b, x0, x0h, sqv);

  // edge construction via MFMA: max+tileMin pass, then pruned mask pass (no memset)
  const int NT = NN / 128, TT = NT * (NT + 1) / 2;  // 32, 528
  k_d2m<false><<<TT, 256, 0, stream>>>(x0h, sqv, dmax, tileMin, nullptr);
  k_d2m<true><<<TT, 256, 0, stream>>>(x0h, sqv, dmax, tileMin, ATa);

  // layer-1 degree (layers 2-3 get dinv from fused gatherA)
  k_deg<<<NN / 4, 256, 0, stream>>>(ATa, dinvA, NN);

  // three GCN + SAGPool + readout layers
  run_layer(stream, x0, 4096, 512, W1, b1, Wpool1, bpool1, 3072, ATa, ATb, dinvA, dinvB,
            ybuf, xg, xp, y2, score, perm, vals, pmax, psum, out);
  run_layer(stream, xp, 3072, 256, W2, b2, Wpool2, bpool2, 2304, ATb, ATa, dinvB, dinvA,
            ybuf, xg, xp, y2, score, perm, vals, pmax, psum, out);
  run_layer(stream, xp, 2304, 256, W3, b3, Wpool3, bpool3, 1728, ATa, nullptr, dinvA, nullptr,
            ybuf, xg, xp, y2, score, perm, vals, pmax, psum, out);
}

// Round 13
// 236.859 us; speedup vs baseline: 1.5774x; 1.2132x over previous
//
#include <hip/hip_runtime.h>
#include <math.h>

#define NN 4096
#define RB 128  // readout stage-1 blocks

typedef __attribute__((ext_vector_type(8))) short bf16x8;
typedef __attribute__((ext_vector_type(4))) float f32x4;

// ---------- helpers ----------
__device__ __forceinline__ unsigned encf(float f) {
  unsigned u = __float_as_uint(f);
  return (u & 0x80000000u) ? ~u : (u | 0x80000000u);
}
__device__ __forceinline__ float decf(unsigned u) {
  return __uint_as_float((u & 0x80000000u) ? (u ^ 0x80000000u) : ~u);
}
__device__ __forceinline__ unsigned short f2bf(float f) {
  unsigned u = __float_as_uint(f);
  return (unsigned short)((u + 0x7fffu + ((u >> 16) & 1u)) >> 16);
}

// ---------- init ----------
__global__ void k_init(float* out, unsigned* dmax) {
  int t = blockIdx.x * 256 + threadIdx.x;
  if (t < 512) out[t] = 0.f;
  if (t == 0) *dmax = 0u;
}

// ---------- pos = img @ Wp + bp ----------
__global__ void k_pos(const float* img, const float* Wp, const float* bp, float* pos) {
  int t = blockIdx.x * 256 + threadIdx.x;
  if (t >= NN * 12) return;
  int i = t / 12, d = t % 12;
  float s = bp[d];
#pragma unroll
  for (int k = 0; k < 6; ++k) s += img[i * 6 + k] * Wp[k * 12 + d];
  pos[t] = s;
}

// ---------- attention, d=12, LDS-tiled keys, branch-free softmax ----------
__global__ __launch_bounds__(256) void k_attn3(const float* pos, float* out) {
  __shared__ float sp[12][256];
  int t = threadIdx.x, lane = t & 63, w = t >> 6;
  int ib = blockIdx.x * 8 + w * 2;  // 2 rows per wave, 8 per block
  float pi[2][12];
#pragma unroll
  for (int r = 0; r < 2; ++r)
#pragma unroll
    for (int d = 0; d < 12; ++d) pi[r][d] = pos[(ib + r) * 12 + d] * 0.28867513459481287f;
  float sl[2] = {0.f, 0.f};
  float acc[2][12] = {};
  const float4* p4 = (const float4*)pos;
  for (int kt = 0; kt < NN; kt += 256) {
    __syncthreads();  // previous tile fully consumed
    int j = kt + t;
    float4 a = p4[j * 3 + 0], b = p4[j * 3 + 1], c = p4[j * 3 + 2];
    sp[0][t] = a.x; sp[1][t] = a.y; sp[2][t] = a.z; sp[3][t] = a.w;
    sp[4][t] = b.x; sp[5][t] = b.y; sp[6][t] = b.z; sp[7][t] = b.w;
    sp[8][t] = c.x; sp[9][t] = c.y; sp[10][t] = c.z; sp[11][t] = c.w;
    __syncthreads();
#pragma unroll
    for (int q = 0; q < 4; ++q) {
      int jj = q * 64 + lane;
      float pj[12];
#pragma unroll
      for (int d = 0; d < 12; ++d) pj[d] = sp[d][jj];
#pragma unroll
      for (int r = 0; r < 2; ++r) {
        float s = 0.f;
#pragma unroll
        for (int d = 0; d < 12; ++d) s = fmaf(pi[r][d], pj[d], s);
        float e = __expf(s);
        sl[r] += e;
#pragma unroll
        for (int d = 0; d < 12; ++d) acc[r][d] = fmaf(e, pj[d], acc[r][d]);
      }
    }
  }
#pragma unroll
  for (int r = 0; r < 2; ++r) {
    float s = sl[r];
#pragma unroll
    for (int o = 32; o > 0; o >>= 1) s += __shfl_xor(s, o);
    float ad[12];
#pragma unroll
    for (int d = 0; d < 12; ++d) {
      ad[d] = acc[r][d];
#pragma unroll
      for (int o = 32; o > 0; o >>= 1) ad[d] += __shfl_xor(ad[d], o);
    }
    if (lane == 0) {
      float inv = 1.f / s;
#pragma unroll
      for (int d = 0; d < 12; ++d) out[(ib + r) * 12 + d] = ad[d] * inv;
    }
  }
}

// ---------- fused layernorms + sumsq + bf16 convert ----------
__global__ __launch_bounds__(256) void k_lnx(const float* f, const float* g, const float* b,
                                             const float* p, const float* pg, const float* pb,
                                             float* x0, unsigned short* x0h, float* sqv) {
  __shared__ float row[512];
  __shared__ float red[256];
  int i = blockIdx.x, t = threadIdx.x;
  float v1 = f[i * 500 + t];
  float v2 = (t < 244) ? f[i * 500 + 256 + t] : 0.f;
  red[t] = v1 + v2; __syncthreads();
  for (int s = 128; s > 0; s >>= 1) { if (t < s) red[t] += red[t + s]; __syncthreads(); }
  float m = red[0] * (1.f / 500.f); __syncthreads();
  float d1 = v1 - m, d2 = v2 - m;
  red[t] = d1 * d1 + ((t < 244) ? d2 * d2 : 0.f); __syncthreads();
  for (int s = 128; s > 0; s >>= 1) { if (t < s) red[t] += red[t + s]; __syncthreads(); }
  float scale = 1.f / sqrtf(red[0] * (1.f / 500.f) + 1e-5f);
  row[t] = d1 * scale * g[t] + b[t];
  if (t < 244) row[256 + t] = d2 * scale * g[256 + t] + b[256 + t];
  if (t >= 244) {  // threads 244..255 handle the 12-wide pos layernorm
    int tt = t - 244;
    float pv[12], pm = 0.f;
#pragma unroll
    for (int d = 0; d < 12; ++d) { pv[d] = p[i * 12 + d]; pm += pv[d]; }
    pm *= (1.f / 12.f);
    float pvar = 0.f;
#pragma unroll
    for (int d = 0; d < 12; ++d) { float dd = pv[d] - pm; pvar += dd * dd; }
    pvar *= (1.f / 12.f);
    float ps = 1.f / sqrtf(pvar + 1e-5f);
    row[500 + tt] = (pv[tt] - pm) * ps * pg[tt] + pb[tt];
  }
  __syncthreads();
  float a = row[t], c = row[256 + t];
  red[t] = a * a + c * c; __syncthreads();
  for (int s = 128; s > 0; s >>= 1) { if (t < s) red[t] += red[t + s]; __syncthreads(); }
  if (t == 0) sqv[i] = red[0];
  x0[(size_t)i * 512 + t] = a;
  x0[(size_t)i * 512 + 256 + t] = c;
  x0h[(size_t)i * 512 + t] = f2bf(a);
  x0h[(size_t)i * 512 + 256 + t] = f2bf(c);
}

// ---------- MFMA d2 tiles (128x128, upper tile pairs): max / mask pass ----------
// T4 pipeline (m201 pattern): double-buffered LDS; issue next panel's 8 DMAs, then
// COUNTED s_waitcnt vmcnt(8), sched_barrier(0), raw s_barrier. No vmcnt(0) drain in
// the loop body. Source pre-swizzled (chunk = (lane&7)^(row&7)); reads same XOR.
// Pass A records per-tile min over gi<gj; pass B skips GEMM when tileMin >= thr and
// zeroes mirror tiles -> no memset.
#define BK 64
template <bool MASK>
__global__ __launch_bounds__(256) void k_d2m(const unsigned short* X, const float* sqv,
                                             unsigned* dmax, float* tileMin,
                                             unsigned char* ATm) {
  __shared__ unsigned short As[2][128 * BK];
  __shared__ unsigned short Bs[2][128 * BK];
  __shared__ float wmax[4], wmin[4];
  const int NT = NN / 128;
  int bid0 = blockIdx.x;
  int bid = (bid0 & 7) * 66 + (bid0 >> 3);  // 528 total, bijective
  int ti = 0, rem = bid;
  while (rem >= NT - ti) { rem -= NT - ti; ++ti; }
  int tj = ti + rem;
  int t = threadIdx.x, lane = t & 63, w = t >> 6;
  int wr = w >> 1, wc = w & 1;  // wave's 64x64 sub-tile
  const unsigned short* Abase = X + (size_t)ti * 128 * 512;
  const unsigned short* Bbase = X + (size_t)tj * 128 * 512;
  int lr = lane >> 3, lc = lane & 7;

  float thr = 0.f;
  if (MASK) {
    thr = 0.5f * decf(*dmax);
    uint4 z = make_uint4(0u, 0u, 0u, 0u);
    if (ti != tj) {  // mirror tile (rows ti, cols tj) never receives mask writes
#pragma unroll
      for (int q0 = 0; q0 < 4; ++q0) {
        int q = t + q0 * 256; int r = q >> 3, c4 = q & 7;
        *(uint4*)(ATm + (size_t)(ti * 128 + r) * NN + tj * 128 + c4 * 16) = z;
      }
    }
    if (tileMin[blockIdx.x] >= thr) {  // no element can pass -> zero tile, skip GEMM
#pragma unroll
      for (int q0 = 0; q0 < 4; ++q0) {
        int q = t + q0 * 256; int r = q >> 3, c4 = q & 7;
        *(uint4*)(ATm + (size_t)(tj * 128 + r) * NN + ti * 128 + c4 * 16) = z;
      }
      return;
    }
  }

  auto stage = [&](int buf, int k0) {  // 8 DMAs per wave (4x A + 4x B)
#pragma unroll
    for (int i = 0; i < 4; ++i) {
      int q = w * 4 + i;
      int r = q * 8 + lr;
      int cs = lc ^ (r & 7);  // pre-swizzled source chunk
      __builtin_amdgcn_global_load_lds(
          (const __attribute__((address_space(1))) unsigned int*)(Abase + (size_t)r * 512 + k0 + cs * 8),
          (__attribute__((address_space(3))) unsigned int*)(&As[buf][q * 512]), 16, 0, 0);
      __builtin_amdgcn_global_load_lds(
          (const __attribute__((address_space(1))) unsigned int*)(Bbase + (size_t)r * 512 + k0 + cs * 8),
          (__attribute__((address_space(3))) unsigned int*)(&Bs[buf][q * 512]), 16, 0, 0);
    }
  };

  stage(0, 0);  // 8 outstanding

  f32x4 acc[4][4] = {};
  int rl = lane & 15, kg = lane >> 4;
  for (int step = 0; step < 8; ++step) {
    int cur = step & 1;
    if (step < 7) {
      stage(cur ^ 1, (step + 1) * BK);  // +8 in flight (16 total)
      asm volatile("s_waitcnt vmcnt(8)" ::: "memory");  // cur's 8 retired (in-order)
    } else {
      asm volatile("s_waitcnt vmcnt(0)" ::: "memory");
    }
    __builtin_amdgcn_sched_barrier(0);
    __builtin_amdgcn_s_barrier();  // all waves' cur panel visible
#pragma unroll
    for (int ks = 0; ks < 2; ++ks) {
      bf16x8 af[4], bq[4];
#pragma unroll
      for (int f = 0; f < 4; ++f) {
        int rA = wr * 64 + f * 16 + rl;
        af[f] = *(const bf16x8*)(&As[cur][rA * BK + (((ks * 4 + kg) ^ (rA & 7)) << 3)]);
        int rB = wc * 64 + f * 16 + rl;
        bq[f] = *(const bf16x8*)(&Bs[cur][rB * BK + (((ks * 4 + kg) ^ (rB & 7)) << 3)]);
      }
#pragma unroll
      for (int a = 0; a < 4; ++a)
#pragma unroll
        for (int b = 0; b < 4; ++b)
          acc[a][b] = __builtin_amdgcn_mfma_f32_16x16x32_bf16(af[a], bq[b], acc[a][b], 0, 0, 0);
    }
    __builtin_amdgcn_sched_barrier(0);  // pin ds_reads before the reuse barrier
    __builtin_amdgcn_s_barrier();       // all reads of cur done before its overwrite
  }
  // C/D layout: col = lane&15, row = (lane>>4)*4 + reg   [m89/m91 verified]
  int rbase = ti * 128 + wr * 64 + ((lane >> 4) << 2);
  int cbase = tj * 128 + wc * 64 + (lane & 15);
  if (!MASK) {
    float lm = -1e30f, lmin = 1e30f;
#pragma unroll
    for (int a = 0; a < 4; ++a) {
      float si[4];
#pragma unroll
      for (int r = 0; r < 4; ++r) si[r] = sqv[rbase + a * 16 + r];
#pragma unroll
      for (int b = 0; b < 4; ++b) {
        int gj = cbase + b * 16;
        float sj = sqv[gj];
#pragma unroll
        for (int r = 0; r < 4; ++r) {
          float d2v = si[r] - 2.f * acc[a][b][r] + sj;
          lm = fmaxf(lm, d2v);
          if (rbase + a * 16 + r < gj) lmin = fminf(lmin, d2v);
        }
      }
    }
#pragma unroll
    for (int o = 32; o > 0; o >>= 1) {
      lm = fmaxf(lm, __shfl_xor(lm, o));
      lmin = fminf(lmin, __shfl_xor(lmin, o));
    }
    if (lane == 0) { wmax[w] = lm; wmin[w] = lmin; }
    __syncthreads();
    if (t == 0) {
      atomicMax(dmax, encf(fmaxf(fmaxf(wmax[0], wmax[1]), fmaxf(wmax[2], wmax[3]))));
      tileMin[blockIdx.x] = fminf(fminf(wmin[0], wmin[1]), fminf(wmin[2], wmin[3]));
    }
  } else {
#pragma unroll
    for (int b = 0; b < 4; ++b) {
      int gj = cbase + b * 16;
      float sj = sqv[gj];
#pragma unroll
      for (int a = 0; a < 4; ++a) {
        int gi0 = rbase + a * 16;
        union { unsigned char c[4]; unsigned u; } m4;
#pragma unroll
        for (int r = 0; r < 4; ++r) {
          float d2v = sqv[gi0 + r] - 2.f * acc[a][b][r] + sj;
          m4.c[r] = (d2v < thr && (gi0 + r) < gj) ? 1 : 0;
        }
        *(unsigned*)(ATm + (size_t)gj * NN + gi0) = m4.u;  // AT[j][i..i+3]
      }
    }
  }
}

// ---------- fp32 GEMM + row scale: C[i][c] = dinv[i] * (A@B)[i][c] ----------
__global__ __launch_bounds__(256) void k_gemm(const float* A, const float* B, const float* dinv,
                                              float* C, int M, int N, int K) {
  __shared__ float As[32][17];
  __shared__ float Bs[16][64];
  int t = threadIdx.x, tx = t & 15, ty = t >> 4;
  int nbx = N >> 6;
  int total = gridDim.x;
  int bid0 = blockIdx.x;
  int bid = (bid0 & 7) * (total >> 3) + (bid0 >> 3);  // bijective: total%8==0
  int m0 = (bid / nbx) * 32, n0 = (bid % nbx) * 64;
  int ar = t >> 3, ac = (t * 2) & 15;   // A stage: 2 floats/thread
  int br = t >> 4, bc = (t & 15) * 4;   // B stage: 4 floats/thread
  float2 ra = *(const float2*)(A + (size_t)(m0 + ar) * K + ac);
  float4 rb = *(const float4*)(B + (size_t)br * N + n0 + bc);
  float acc[2][4] = {};
  for (int k0 = 0; k0 < K; k0 += 16) {
    As[ar][ac] = ra.x; As[ar][ac + 1] = ra.y;
    *(float4*)(&Bs[br][bc]) = rb;
    __syncthreads();
    if (k0 + 16 < K) {  // prefetch next panel (overlaps compute)
      ra = *(const float2*)(A + (size_t)(m0 + ar) * K + k0 + 16 + ac);
      rb = *(const float4*)(B + (size_t)(k0 + 16 + br) * N + n0 + bc);
    }
#pragma unroll
    for (int kk = 0; kk < 16; ++kk) {
      float av[2], bv[4];
#pragma unroll
      for (int u = 0; u < 2; ++u) av[u] = As[ty * 2 + u][kk];
#pragma unroll
      for (int u = 0; u < 4; ++u) bv[u] = Bs[kk][tx * 4 + u];
#pragma unroll
      for (int a = 0; a < 2; ++a)
#pragma unroll
        for (int b2 = 0; b2 < 4; ++b2) acc[a][b2] = fmaf(av[a], bv[b2], acc[a][b2]);
    }
    __syncthreads();
  }
#pragma unroll
  for (int a = 0; a < 2; ++a) {
    float dv = dinv[m0 + ty * 2 + a];
#pragma unroll
    for (int b2 = 0; b2 < 4; ++b2)
      C[(size_t)(m0 + ty * 2 + a) * N + n0 + tx * 4 + b2] = acc[a][b2] * dv;
  }
}

// ---------- dinv[j] = 1/sqrt(1 + sum_i AT[j][i])  (layer 1 only) ----------
__global__ __launch_bounds__(256) void k_deg(const unsigned char* ATm, float* dinv, int n) {
  int w = threadIdx.x >> 6, lane = threadIdx.x & 63;
  int j = blockIdx.x * 4 + w;
  if (j >= n) return;
  const uint4* row = (const uint4*)(ATm + (size_t)j * n);
  int sum = 0;
  for (int p = lane; p < n / 16; p += 64) {
    uint4 v = row[p];
    unsigned a = v.x, b = v.y, c = v.z, d = v.w;
    sum += (a & 0xff) + ((a >> 8) & 0xff) + ((a >> 16) & 0xff) + (a >> 24);
    sum += (b & 0xff) + ((b >> 8) & 0xff) + ((b >> 16) & 0xff) + (b >> 24);
    sum += (c & 0xff) + ((c >> 8) & 0xff) + ((c >> 16) & 0xff) + (c >> 24);
    sum += (d & 0xff) + ((d >> 8) & 0xff) + ((d >> 16) & 0xff) + (d >> 24);
  }
  for (int s = 32; s > 0; s >>= 1) sum += __shfl_down(sum, s);
  if (lane == 0) dinv[j] = 1.f / sqrtf((float)(1 + sum));
}

// ---------- fused: xg row + relu + y2[j] = dinv[j]*dot(xg[j], Wpool) ----------
// Fast path: dinv[j]==1.0f  <=>  deg[j]==0 (1/sqrt(1)=1 exact; deg>=1 -> <=0.7072)
// -> no neighbors, acc stays y[j]; skip the whole mask scan. Bit-exact (x*1.0, +0).
__global__ __launch_bounds__(256) void k_agg(const float* y, const unsigned char* ATm,
                                             const float* dinv, const float* bias,
                                             const float* Wpool, float* out, float* y2, int n) {
  __shared__ unsigned char mrow[256];
  __shared__ int s_any;
  __shared__ float red[256];
  int j = blockIdx.x, t = threadIdx.x;
  float dj = dinv[j];
  float acc = y[(size_t)j * 256 + t];
  if (dj != 1.0f) {
    for (int i0 = 0; i0 < n; i0 += 256) {
      if (t == 0) s_any = 0;
      __syncthreads();
      unsigned char m = ATm[(size_t)j * n + i0 + t];
      mrow[t] = m;
      if (m) s_any = 1;
      __syncthreads();
      if (s_any) {
        for (int u = 0; u < 256; ++u)
          if (mrow[u]) acc += y[(size_t)(i0 + u) * 256 + t];
      }
      __syncthreads();
    }
  }
  float o = fmaxf(dj * acc + bias[t], 0.f);
  out[(size_t)j * 256 + t] = o;
  red[t] = o * Wpool[t]; __syncthreads();
  for (int s = 128; s > 0; s >>= 1) { if (t < s) red[t] += red[t + s]; __syncthreads(); }
  if (t == 0) y2[j] = dj * red[0];
}

// ---------- score[j] = tanh(dinv[j]*(y2[j] + sum_{i:AT[j,i]} y2[i]) + bpool) ----------
__global__ __launch_bounds__(256) void k_scorek(const float* y2, const unsigned char* ATm,
                                                const float* dinv, const float* bp,
                                                float* score, int n) {
  int w = threadIdx.x >> 6, lane = threadIdx.x & 63;
  int j = blockIdx.x * 4 + w;
  if (j >= n) return;
  float dj = dinv[j];
  float s = 0.f;
  if (dj != 1.0f) {  // deg>0: scan the row
    const uint4* row = (const uint4*)(ATm + (size_t)j * n);
    for (int p = lane; p < n / 16; p += 64) {
      uint4 v = row[p];
      if (v.x | v.y | v.z | v.w) {
        int base = p * 16;
#pragma unroll
        for (int q = 0; q < 4; ++q) {
          unsigned u = (&v.x)[q];
#pragma unroll
          for (int b2 = 0; b2 < 4; ++b2)
            if ((u >> (8 * b2)) & 0xffu) s += y2[base + q * 4 + b2];
        }
      }
    }
    for (int sh = 32; sh > 0; sh >>= 1) s += __shfl_down(s, sh);
  }
  if (lane == 0) score[j] = tanhf(dj * (y2[j] + s) + bp[0]);
}

// ---------- radix-select top-k (exact PyG set semantics; output in index order) ----------
__global__ __launch_bounds__(1024) void k_topsel(const float* score, int n, int k,
                                                 int* perm, float* vals) {
  __shared__ unsigned keys[4096];
  __shared__ unsigned hist[256];
  __shared__ unsigned s_state[2];  // [0]=prefix(cutoff), [1]=need(ties to take)
  __shared__ unsigned woff[16];
  int t = threadIdx.x, lane = t & 63, w = t >> 6;
  for (int i = t; i < 4096; i += 1024) keys[i] = (i < n) ? encf(score[i]) : 0u;
  if (t == 0) { s_state[0] = 0u; s_state[1] = (unsigned)k; }
  __syncthreads();

  for (int pass = 0; pass < 4; ++pass) {
    int shift = 24 - pass * 8;
    if (t < 256) hist[t] = 0u;
    __syncthreads();
    unsigned prefix = s_state[0];
    unsigned need = s_state[1];
    unsigned pmask = pass ? (0xFFFFFFFFu << (shift + 8)) : 0u;
    for (int i = t; i < n; i += 1024) {
      unsigned kk = keys[i];
      if ((kk & pmask) == prefix) atomicAdd(&hist[(kk >> shift) & 255u], 1u);
    }
    __syncthreads();
    if (w == 0) {
      unsigned h[4], suf[4];
#pragma unroll
      for (int r = 0; r < 4; ++r) h[r] = hist[lane * 4 + r];
      suf[3] = h[3]; suf[2] = h[2] + suf[3]; suf[1] = h[1] + suf[2]; suf[0] = h[0] + suf[1];
      unsigned lsum = suf[0];
      unsigned s = lsum;
#pragma unroll
      for (int off = 1; off < 64; off <<= 1) {
        unsigned o = __shfl_down(s, off);
        if (lane + off < 64) s += o;
      }
      unsigned Hl = s - lsum;
      int cand = -1; unsigned cumAt = 0, histAt = 0;
#pragma unroll
      for (int r = 0; r < 4; ++r) {
        unsigned c = Hl + suf[r];
        if (c >= need) { cand = lane * 4 + r; cumAt = c; histAt = h[r]; }
      }
      int gmax = cand;
#pragma unroll
      for (int off = 32; off > 0; off >>= 1) {
        int o = __shfl_xor(gmax, off);
        gmax = o > gmax ? o : gmax;
      }
      if (cand == gmax && cand >= 0) {
        s_state[0] = prefix | ((unsigned)cand << shift);
        s_state[1] = need - (cumAt - histAt);
      }
    }
    __syncthreads();
  }
  unsigned cutoff = s_state[0];
  unsigned tcount = s_state[1];
  unsigned G = (unsigned)k - tcount;

  int i0 = t * 4;
  unsigned loc[4], cnt = 0;
#pragma unroll
  for (int r = 0; r < 4; ++r) {
    unsigned kk = keys[i0 + r];
    unsigned g = (kk > cutoff) ? 1u : 0u;
    unsigned e = (kk == cutoff) ? 1u : 0u;
    loc[r] = cnt;
    cnt += (g << 16) | e;
  }
  unsigned inc = cnt;
#pragma unroll
  for (int off = 1; off < 64; off <<= 1) {
    unsigned o = __shfl_up(inc, off);
    if (lane >= off) inc += o;
  }
  if (lane == 63) woff[w] = inc;
  __syncthreads();
  if (t == 0) {
    unsigned run = 0;
    for (int q = 0; q < 16; ++q) { unsigned v = woff[q]; woff[q] = run; run += v; }
  }
  __syncthreads();
  unsigned base = woff[w] + (inc - cnt);
#pragma unroll
  for (int r = 0; r < 4; ++r) {
    unsigned kk = keys[i0 + r];
    unsigned p = base + loc[r];
    if (kk > cutoff) {
      unsigned pos = p >> 16;
      perm[pos] = i0 + r; vals[pos] = decf(kk);
    } else if (kk == cutoff) {
      unsigned pe = p & 0xffffu;
      if (pe < tcount) { perm[G + pe] = i0 + r; vals[G + pe] = decf(kk); }
    }
  }
}

// ---------- fused gather + readout partials: xp[r] = xg[perm[r]]*vals[r]; max/sum ----------
__global__ __launch_bounds__(256) void k_gxp(const float* xg, const int* perm, const float* vals,
                                             float* xp, float* pmax, float* psum, int k) {
  int b = blockIdx.x, t = threadIdx.x;
  float m = -1e30f, s = 0.f;
  for (int r = b; r < k; r += RB) {
    float v = xg[(size_t)perm[r] * 256 + t] * vals[r];
    xp[(size_t)r * 256 + t] = v;
    m = fmaxf(m, v); s += v;
  }
  pmax[b * 256 + t] = m; psum[b * 256 + t] = s;
}
__global__ void k_rfin(const float* pmax, const float* psum, float* out, int k) {
  int t = threadIdx.x;
  float m = -1e30f, s = 0.f;
  for (int q = 0; q < RB; ++q) { m = fmaxf(m, pmax[q * 256 + t]); s += psum[q * 256 + t]; }
  out[t] += m;
  out[256 + t] += s / (float)k;
}

// ---------- ATnew[c][r] = ATold[perm[c]][perm[r]]  + fused deg for next layer ----------
// Fast path: dinvCur[sperm[c]]==1.0f -> source row all-zero -> vectorized zero writes.
__global__ __launch_bounds__(256) void k_gatherA(const unsigned char* ATold, const int* perm,
                                                 const float* dinvCur,
                                                 unsigned char* ATnew, float* dinvNext,
                                                 int nold, int kn) {
  __shared__ int sperm[4096];
  __shared__ int redi[256];
  int t = threadIdx.x, c = blockIdx.x;
  for (int r = t; r < kn; r += 256) sperm[r] = perm[r];
  __syncthreads();
  int src = sperm[c];
  unsigned char* orow = ATnew + (size_t)c * kn;
  if (dinvCur[src] == 1.0f) {  // empty source row (kn % 16 == 0)
    uint4 z = make_uint4(0u, 0u, 0u, 0u);
    for (int r = t; r < kn / 16; r += 256) ((uint4*)orow)[r] = z;
    if (t == 0) dinvNext[c] = 1.0f;
    return;
  }
  const unsigned char* row = ATold + (size_t)src * nold;
  int cnt = 0;
  for (int r = t; r < kn; r += 256) { unsigned char v = row[sperm[r]]; orow[r] = v; cnt += v; }
  redi[t] = cnt; __syncthreads();
  for (int s = 128; s > 0; s >>= 1) { if (t < s) redi[t] += redi[t + s]; __syncthreads(); }
  if (t == 0) dinvNext[c] = 1.f / sqrtf((float)(1 + redi[0]));
}

// ---------- host-side layer driver ----------
static void run_layer(hipStream_t stream, const float* x_in, int n, int inC,
                      const float* W, const float* b, const float* Wpool, const float* bpool,
                      int k, const unsigned char* ATcur, unsigned char* ATnext,
                      const float* dinvCur, float* dinvNext,
                      float* ybuf, float* xg, float* xp, float* y2,
                      float* score, int* perm, float* vals, float* pmax, float* psum, float* out) {
  k_gemm<<<(n / 32) * 4, 256, 0, stream>>>(x_in, W, dinvCur, ybuf, n, 256, inC);
  k_agg<<<n, 256, 0, stream>>>(ybuf, ATcur, dinvCur, b, Wpool, xg, y2, n);
  k_scorek<<<n / 4, 256, 0, stream>>>(y2, ATcur, dinvCur, bpool, score, n);
  k_topsel<<<1, 1024, 0, stream>>>(score, n, k, perm, vals);
  k_gxp<<<RB, 256, 0, stream>>>(xg, perm, vals, xp, pmax, psum, k);
  k_rfin<<<1, 256, 0, stream>>>(pmax, psum, out, k);
  if (ATnext) k_gatherA<<<k, 256, 0, stream>>>(ATcur, perm, dinvCur, ATnext, dinvNext, n, k);
}

extern "C" void kernel_launch(void* const* d_in, const int* in_sizes, int n_in,
                              void* d_out, int out_size, void* d_ws, size_t ws_size,
                              hipStream_t stream) {
  const float* feature = (const float*)d_in[0];
  const float* img     = (const float*)d_in[1];
  const float* Wp      = (const float*)d_in[2];
  const float* bp      = (const float*)d_in[3];
  const float* ln_f_g  = (const float*)d_in[4];
  const float* ln_f_b  = (const float*)d_in[5];
  const float* ln_p_g  = (const float*)d_in[6];
  const float* ln_p_b  = (const float*)d_in[7];
  const float* W1 = (const float*)d_in[8];   const float* b1 = (const float*)d_in[9];
  const float* Wpool1 = (const float*)d_in[10]; const float* bpool1 = (const float*)d_in[11];
  const float* W2 = (const float*)d_in[12];  const float* b2 = (const float*)d_in[13];
  const float* Wpool2 = (const float*)d_in[14]; const float* bpool2 = (const float*)d_in[15];
  const float* W3 = (const float*)d_in[16];  const float* b3 = (const float*)d_in[17];
  const float* Wpool3 = (const float*)d_in[18]; const float* bpool3 = (const float*)d_in[19];
  float* out = (float*)d_out;
  (void)in_sizes; (void)n_in; (void)out_size; (void)ws_size;

  char* w = (char*)d_ws;
  size_t off = 0;
  auto alloc = [&](size_t bytes) -> char* {
    off = (off + 255) & ~(size_t)255;
    char* p = w + off;
    off += bytes;
    return p;
  };
  float* pos0 = (float*)alloc((size_t)NN * 12 * 4);
  float* pos1 = (float*)alloc((size_t)NN * 12 * 4);
  float* x0   = (float*)alloc((size_t)NN * 512 * 4);
  unsigned short* x0h = (unsigned short*)alloc((size_t)NN * 512 * 2);
  float* sqv  = (float*)alloc((size_t)NN * 4);
  unsigned* dmax = (unsigned*)alloc(4);
  float* tileMin = (float*)alloc(528 * 4);
  float* dinvA = (float*)alloc((size_t)NN * 4);
  float* dinvB = (float*)alloc((size_t)NN * 4);
  float* ybuf = (float*)alloc((size_t)NN * 256 * 4);
  float* xg   = (float*)alloc((size_t)NN * 256 * 4);
  float* xp   = (float*)alloc((size_t)NN * 256 * 4);
  float* y2   = (float*)alloc((size_t)NN * 4);
  float* score= (float*)alloc((size_t)NN * 4);
  int*   perm = (int*)alloc((size_t)NN * 4);
  float* vals = (float*)alloc((size_t)NN * 4);
  float* pmax = (float*)alloc(RB * 256 * 4);
  float* psum = (float*)alloc(RB * 256 * 4);
  unsigned char* ATa = (unsigned char*)alloc((size_t)NN * NN);
  unsigned char* ATb = (unsigned char*)alloc((size_t)3072 * 3072);

  // preamble
  k_init<<<2, 256, 0, stream>>>(out, dmax);
  k_pos<<<(NN * 12 + 255) / 256, 256, 0, stream>>>(img, Wp, bp, pos0);
  k_attn3<<<NN / 8, 256, 0, stream>>>(pos0, pos1);
  k_lnx<<<NN, 256, 0, stream>>>(feature, ln_f_g, ln_f_b, pos1, ln_p_g, ln_p_b, x0, x0h, sqv);

  // edge construction via MFMA: max+tileMin pass, then pruned mask pass (no memset)
  const int NT = NN / 128, TT = NT * (NT + 1) / 2;  // 32, 528
  k_d2m<false><<<TT, 256, 0, stream>>>(x0h, sqv, dmax, tileMin, nullptr);
  k_d2m<true><<<TT, 256, 0, stream>>>(x0h, sqv, dmax, tileMin, ATa);

  // layer-1 degree (layers 2-3 get dinv from fused gatherA)
  k_deg<<<NN / 4, 256, 0, stream>>>(ATa, dinvA, NN);

  // three GCN + SAGPool + readout layers
  run_layer(stream, x0, 4096, 512, W1, b1, Wpool1, bpool1, 3072, ATa, ATb, dinvA, dinvB,
            ybuf, xg, xp, y2, score, perm, vals, pmax, psum, out);
  run_layer(stream, xp, 3072, 256, W2, b2, Wpool2, bpool2, 2304, ATb, ATa, dinvB, dinvA,
            ybuf, xg, xp, y2, score, perm, vals, pmax, psum, out);
  run_layer(stream, xp, 2304, 256, W3, b3, Wpool3, bpool3, 1728, ATa, nullptr, dinvA, nullptr,
            ybuf, xg, xp, y2, score, perm, vals, pmax, psum, out);
}